// Round 1
// baseline (539.539 us; speedup 1.0000x reference)
//
#include <hip/hip_runtime.h>

// MultiHeadAttention fwd: B=4, S=2048, D=1024, H=16, DK=64.
// Strategy: cast to bf16, all 4 projections + attention via mfma_f32_16x16x32_bf16
// (f32 accumulate). ws layout (75.5 MB):
//   [0,8MB)    WTq/WTk/WTv/WTo  bf16 [N][K] (pre-transposed weights)
//   [8,25MB)   Xb   bf16 input cast buffer (reused as Vt [bh][dk][s] after V proj)
//   [25,42MB)  Qp   bf16 [M][D]
//   [42,59MB)  Kp   bf16 [M][D]
//   [59,76MB)  Vp   bf16 [M][D] (reused as ctx after vtrans)

#define B_ 4
#define S_ 2048
#define D_ 1024
#define H_ 16
#define M_ 8192  // B_*S_

typedef unsigned short u16;
typedef float f32x4 __attribute__((ext_vector_type(4)));
typedef __bf16 bf16x8 __attribute__((ext_vector_type(8)));

__device__ __forceinline__ u16 f2bf(float f) {
  unsigned int x = __float_as_uint(f);
  x = (x + 0x7fffu + ((x >> 16) & 1u)) >> 16;  // RNE
  return (u16)x;
}

__device__ __forceinline__ f32x4 mfma16(bf16x8 a, bf16x8 b, f32x4 c) {
  return __builtin_amdgcn_mfma_f32_16x16x32_bf16(a, b, c, 0, 0, 0);
}

// ---------------- f32 -> bf16 cast (vectorized) ----------------
__global__ __launch_bounds__(256) void cast_bf16_kernel(const float4* __restrict__ in,
                                                        ushort4* __restrict__ out, int n4) {
  int i = blockIdx.x * 256 + threadIdx.x;
  int stride = gridDim.x * 256;
  for (; i < n4; i += stride) {
    float4 v = in[i];
    ushort4 o;
    o.x = f2bf(v.x); o.y = f2bf(v.y); o.z = f2bf(v.z); o.w = f2bf(v.w);
    out[i] = o;
  }
}

// ---------------- W [K][N] f32 -> WT [N][K] bf16 ----------------
__global__ __launch_bounds__(256) void wtrans_kernel(const float* __restrict__ W,
                                                     u16* __restrict__ WT) {
  __shared__ float tile[32][33];
  int k0 = blockIdx.x * 32, n0 = blockIdx.y * 32;
  int t = threadIdx.x, c = t & 31, r0 = t >> 5;
#pragma unroll
  for (int i = 0; i < 4; ++i)
    tile[r0 + i * 8][c] = W[(size_t)(k0 + r0 + i * 8) * D_ + n0 + c];
  __syncthreads();
#pragma unroll
  for (int i = 0; i < 4; ++i)
    WT[(size_t)(n0 + r0 + i * 8) * D_ + k0 + c] = f2bf(tile[c][r0 + i * 8]);
}

// ---------------- Vp [M][D] bf16 -> Vt [64 bh][64 dk][2048 s] ----------------
__global__ __launch_bounds__(256) void vtrans_kernel(const u16* __restrict__ Vp,
                                                     u16* __restrict__ Vt) {
  __shared__ u16 tile[64][65];
  int bx = blockIdx.x;          // 64 bh * 32 s-tiles
  int bh = bx >> 5;
  int s0 = (bx & 31) * 64;
  int b = bh >> 4, h = bh & 15;
  int t = threadIdx.x, c = t & 63, r0 = t >> 6;
#pragma unroll
  for (int i = 0; i < 16; ++i) {
    int s = r0 + i * 4;
    tile[s][c] = Vp[(size_t)(b * S_ + s0 + s) * D_ + h * 64 + c];
  }
  __syncthreads();
#pragma unroll
  for (int i = 0; i < 16; ++i) {
    int dk = r0 + i * 4;
    Vt[((size_t)bh * 64 + dk) * S_ + s0 + c] = tile[c][dk];
  }
}

// ---------------- GEMM: C[M][1024] = A[M][1024](bf16) @ WT^T + bias ----------------
// 128x128 tile, BK=64, 256 threads (4 waves, 2x2), 4x4 16x16 frags/wave.
// LDS tiles [128][64] bf16, 16B chunks XOR-swizzled by (row&7).
template <bool OUT_F32>
__global__ __launch_bounds__(256) void gemm_kernel(const u16* __restrict__ A,
                                                   const u16* __restrict__ BT,
                                                   const float* __restrict__ bias,
                                                   void* __restrict__ out) {
  __shared__ __align__(16) u16 ldsA[128 * 64];
  __shared__ __align__(16) u16 ldsB[128 * 64];
  int bx = blockIdx.x;                    // 512 = 64 Mtiles * 8 Ntiles
  int swz = (bx & 7) * 64 + (bx >> 3);    // bijective XCD swizzle (512%8==0)
  int bm = swz >> 3, bn = swz & 7;
  int t = threadIdx.x, w = t >> 6, lane = t & 63;
  int wm = w >> 1, wn = w & 1;
  int l15 = lane & 15, hi = lane >> 4;

  f32x4 acc[4][4];
#pragma unroll
  for (int m = 0; m < 4; ++m)
#pragma unroll
    for (int n = 0; n < 4; ++n) acc[m][n] = (f32x4){0.f, 0.f, 0.f, 0.f};

  int sc_ = t & 7, sr = t >> 3;  // staging: chunk-in-row, row base (4 rows/thread)
  size_t aBase = (size_t)(bm * 128) * D_;
  size_t bBase = (size_t)(bn * 128) * D_;

  for (int kk = 0; kk < D_; kk += 64) {
    __syncthreads();
#pragma unroll
    for (int i = 0; i < 4; ++i) {
      int r = sr + i * 32;
      uint4 va = *(const uint4*)(A + aBase + (size_t)r * D_ + kk + sc_ * 8);
      *(uint4*)(ldsA + r * 64 + ((sc_ ^ (r & 7)) << 3)) = va;
      uint4 vb = *(const uint4*)(BT + bBase + (size_t)r * D_ + kk + sc_ * 8);
      *(uint4*)(ldsB + r * 64 + ((sc_ ^ (r & 7)) << 3)) = vb;
    }
    __syncthreads();
#pragma unroll
    for (int ks = 0; ks < 2; ++ks) {
      bf16x8 af[4], bfr[4];
#pragma unroll
      for (int m = 0; m < 4; ++m) {
        int r = wm * 64 + m * 16 + l15;
        af[m] = *(const bf16x8*)(ldsA + r * 64 + ((((ks << 2) + hi) ^ (r & 7)) << 3));
      }
#pragma unroll
      for (int n = 0; n < 4; ++n) {
        int r = wn * 64 + n * 16 + l15;
        bfr[n] = *(const bf16x8*)(ldsB + r * 64 + ((((ks << 2) + hi) ^ (r & 7)) << 3));
      }
#pragma unroll
      for (int m = 0; m < 4; ++m)
#pragma unroll
        for (int n = 0; n < 4; ++n)
          acc[m][n] = mfma16(af[m], bfr[n], acc[m][n]);
    }
  }

#pragma unroll
  for (int m = 0; m < 4; ++m)
#pragma unroll
    for (int n = 0; n < 4; ++n) {
      int row = bm * 128 + wm * 64 + m * 16 + hi * 4;
      int col = bn * 128 + wn * 64 + n * 16 + l15;
      float bv = bias[col];
#pragma unroll
      for (int r = 0; r < 4; ++r) {
        float v = acc[m][n][r] + bv;
        if (OUT_F32)
          ((float*)out)[(size_t)(row + r) * D_ + col] = v;
        else
          ((u16*)out)[(size_t)(row + r) * D_ + col] = f2bf(v);
      }
    }
}

// ---------------- Flash attention ----------------
// Block: 256 threads (4 waves), 64 q-rows (16/wave), K/V tiles of 128 keys.
// ldsK [128 s][64 dk], ldsV [64 dk][128 s], ldsP per-wave [16 q][128 k]; all
// 16B-chunk XOR-swizzled by (row&7). Online softmax: C-layout row=hi*4+r (q),
// col=l15 (key); row reductions via shfl_xor over the 16-lane col group.
__global__ __launch_bounds__(256) void attn_kernel(const u16* __restrict__ Qp,
                                                   const u16* __restrict__ Kp,
                                                   const u16* __restrict__ Vt,
                                                   u16* __restrict__ ctx) {
  __shared__ __align__(16) u16 ldsK[128 * 64];
  __shared__ __align__(16) u16 ldsV[64 * 128];
  __shared__ __align__(16) u16 ldsP[4 * 16 * 128];

  int bx = blockIdx.x;                      // 2048 = 64 bh * 32 qtiles
  int swz = (bx & 7) * 256 + (bx >> 3);     // 8 bh per XCD -> KV L2-resident
  int bh = swz >> 5;
  int qt = swz & 31;
  int b = bh >> 4, h = bh & 15;
  int qbase = qt * 64;

  int t = threadIdx.x, w = t >> 6, lane = t & 63;
  int l15 = lane & 15, hi = lane >> 4;
  u16* Pw = ldsP + w * (16 * 128);

  bf16x8 qf[2];  // A-frags: lane holds Q[q=l15][k=ks*32+hi*8 ..+8]
  {
    const u16* qptr = Qp + (size_t)(b * S_ + qbase + w * 16 + l15) * D_ + h * 64;
    qf[0] = *(const bf16x8*)(qptr + hi * 8);
    qf[1] = *(const bf16x8*)(qptr + 32 + hi * 8);
  }

  float mrow[4], lrow[4];
  f32x4 accO[4];
#pragma unroll
  for (int r = 0; r < 4; ++r) { mrow[r] = -1e30f; lrow[r] = 0.f; }
#pragma unroll
  for (int g = 0; g < 4; ++g) accO[g] = (f32x4){0.f, 0.f, 0.f, 0.f};

  int sc8 = t & 7, sr8 = t >> 3;    // K staging: 8 chunks/row
  int sc16 = t & 15, sr16 = t >> 4; // V staging: 16 chunks/row

  for (int kt = 0; kt < 16; ++kt) {   // S_/128
    __syncthreads();
#pragma unroll
    for (int i = 0; i < 4; ++i) {
      int r = sr8 + i * 32;
      uint4 v = *(const uint4*)(Kp + (size_t)(b * S_ + kt * 128 + r) * D_ + h * 64 + sc8 * 8);
      *(uint4*)(ldsK + r * 64 + ((sc8 ^ (r & 7)) << 3)) = v;
    }
#pragma unroll
    for (int i = 0; i < 4; ++i) {
      int r = sr16 + i * 16;
      uint4 v = *(const uint4*)(Vt + ((size_t)bh * 64 + r) * S_ + kt * 128 + sc16 * 8);
      *(uint4*)(ldsV + r * 128 + ((sc16 ^ (r & 7)) << 3)) = v;
    }
    __syncthreads();

    // QK^T: scores[q=hi*4+r][key=f*16+l15]
    f32x4 sc[8];
#pragma unroll
    for (int f = 0; f < 8; ++f) {
      f32x4 z = (f32x4){0.f, 0.f, 0.f, 0.f};
#pragma unroll
      for (int ks = 0; ks < 2; ++ks) {
        int r = f * 16 + l15;
        bf16x8 kf = *(const bf16x8*)(ldsK + r * 64 + ((((ks << 2) + hi) ^ (r & 7)) << 3));
        z = mfma16(qf[ks], kf, z);
      }
      sc[f] = z * 0.125f;  // 1/sqrt(DK)
    }

    // online softmax
    float mnew[4];
#pragma unroll
    for (int r = 0; r < 4; ++r) mnew[r] = mrow[r];
#pragma unroll
    for (int f = 0; f < 8; ++f)
#pragma unroll
      for (int r = 0; r < 4; ++r) mnew[r] = fmaxf(mnew[r], sc[f][r]);
#pragma unroll
    for (int off = 1; off <= 8; off <<= 1)
#pragma unroll
      for (int r = 0; r < 4; ++r) mnew[r] = fmaxf(mnew[r], __shfl_xor(mnew[r], off, 64));

    float alpha[4], rsum[4];
#pragma unroll
    for (int r = 0; r < 4; ++r) {
      alpha[r] = __expf(mrow[r] - mnew[r]);
      mrow[r] = mnew[r];
      rsum[r] = 0.f;
    }
#pragma unroll
    for (int f = 0; f < 8; ++f)
#pragma unroll
      for (int r = 0; r < 4; ++r) {
        float p = __expf(sc[f][r] - mnew[r]);
        sc[f][r] = p;
        rsum[r] += p;
      }
#pragma unroll
    for (int off = 1; off <= 8; off <<= 1)
#pragma unroll
      for (int r = 0; r < 4; ++r) rsum[r] += __shfl_xor(rsum[r], off, 64);
#pragma unroll
    for (int r = 0; r < 4; ++r) lrow[r] = lrow[r] * alpha[r] + rsum[r];
#pragma unroll
    for (int g = 0; g < 4; ++g)
#pragma unroll
      for (int r = 0; r < 4; ++r) accO[g][r] *= alpha[r];

    // P -> per-wave LDS (bf16), swizzled for contiguous A-frag reads
#pragma unroll
    for (int f = 0; f < 8; ++f) {
      int key = f * 16 + l15;
      int chunk = key >> 3, within = key & 7;
#pragma unroll
      for (int r = 0; r < 4; ++r) {
        int q = hi * 4 + r;
        Pw[q * 128 + ((chunk ^ (q & 7)) << 3) + within] = f2bf(sc[f][r]);
      }
    }

    // PV: O[q][dk=g*16+l15] += P @ V
#pragma unroll
    for (int ks = 0; ks < 4; ++ks) {
      bf16x8 pf = *(const bf16x8*)(Pw + l15 * 128 + ((((ks << 2) + hi) ^ (l15 & 7)) << 3));
#pragma unroll
      for (int g = 0; g < 4; ++g) {
        int r = g * 16 + l15;
        bf16x8 vf = *(const bf16x8*)(ldsV + r * 128 + ((((ks << 2) + hi) ^ (r & 7)) << 3));
        accO[g] = mfma16(pf, vf, accO[g]);
      }
    }
  }

#pragma unroll
  for (int r = 0; r < 4; ++r) {
    float inv = 1.0f / lrow[r];
    int qrow = qbase + w * 16 + hi * 4 + r;
    u16* cp = ctx + (size_t)(b * S_ + qrow) * D_ + h * 64;
#pragma unroll
    for (int g = 0; g < 4; ++g)
      cp[g * 16 + l15] = f2bf(accO[g][r] * inv);
  }
}

extern "C" void kernel_launch(void* const* d_in, const int* in_sizes, int n_in,
                              void* d_out, int out_size, void* d_ws, size_t ws_size,
                              hipStream_t stream) {
  const float* query = (const float*)d_in[0];
  const float* key   = (const float*)d_in[1];
  const float* value = (const float*)d_in[2];
  const float* Wq = (const float*)d_in[3];
  const float* bq = (const float*)d_in[4];
  const float* Wk = (const float*)d_in[5];
  const float* bk = (const float*)d_in[6];
  const float* Wv = (const float*)d_in[7];
  const float* bv = (const float*)d_in[8];
  const float* Wo = (const float*)d_in[9];
  const float* bo = (const float*)d_in[10];

  char* ws = (char*)d_ws;
  const size_t WT_BYTES  = (size_t)D_ * D_ * 2;   // 2 MB
  const size_t MAT_BYTES = (size_t)M_ * D_ * 2;   // 16.78 MB
  u16* WTq = (u16*)(ws);
  u16* WTk = (u16*)(ws + WT_BYTES);
  u16* WTv = (u16*)(ws + 2 * WT_BYTES);
  u16* WTo = (u16*)(ws + 3 * WT_BYTES);
  u16* Xb  = (u16*)(ws + 4 * WT_BYTES);
  u16* Qp  = (u16*)(ws + 4 * WT_BYTES + MAT_BYTES);
  u16* Kp  = (u16*)(ws + 4 * WT_BYTES + 2 * MAT_BYTES);
  u16* Vp  = (u16*)(ws + 4 * WT_BYTES + 3 * MAT_BYTES);
  u16* Vt  = Xb;   // input-cast buffer is free after its projection
  u16* ctx = Vp;   // Vp is free after vtrans

  dim3 blk(256);
  dim3 wgrid(32, 32);
  wtrans_kernel<<<wgrid, blk, 0, stream>>>(Wq, WTq);
  wtrans_kernel<<<wgrid, blk, 0, stream>>>(Wk, WTk);
  wtrans_kernel<<<wgrid, blk, 0, stream>>>(Wv, WTv);
  wtrans_kernel<<<wgrid, blk, 0, stream>>>(Wo, WTo);

  const int n4 = M_ * D_ / 4;
  cast_bf16_kernel<<<2048, blk, 0, stream>>>((const float4*)query, (ushort4*)Xb, n4);
  gemm_kernel<false><<<512, blk, 0, stream>>>(Xb, WTq, bq, Qp);
  cast_bf16_kernel<<<2048, blk, 0, stream>>>((const float4*)key, (ushort4*)Xb, n4);
  gemm_kernel<false><<<512, blk, 0, stream>>>(Xb, WTk, bk, Kp);
  cast_bf16_kernel<<<2048, blk, 0, stream>>>((const float4*)value, (ushort4*)Xb, n4);
  gemm_kernel<false><<<512, blk, 0, stream>>>(Xb, WTv, bv, Vp);
  vtrans_kernel<<<2048, blk, 0, stream>>>(Vp, Vt);
  attn_kernel<<<2048, blk, 0, stream>>>(Qp, Kp, Vt, ctx);
  gemm_kernel<true><<<512, blk, 0, stream>>>(ctx, WTo, bo, d_out);
}

// Round 6
// 403.512 us; speedup vs baseline: 1.3371x; 1.3371x over previous
//
#include <hip/hip_runtime.h>

// MultiHeadAttention fwd: B=4, S=2048, D=1024, H=16, DK=64.
// bf16 MFMA everywhere. Round 3 (3rd resubmit; rounds 3-5 infra failures):
// fix attn O-rescale — alpha is per-q-row; O's 16 C-regs are 16 DIFFERENT q
// rows, so alpha must be shfl-redistributed (rescale gated exactly: only when
// a lane's tile-max exceeds its running max).
// ws layout (75.5 MB): 4x WT bf16 [N][K] | Xb (reused as Vt) | Qp | Kp | Vp(->ctx)

#define B_ 4
#define S_ 2048
#define D_ 1024
#define H_ 16
#define M_ 8192  // B_*S_

typedef unsigned short u16;
typedef unsigned int u32;
typedef float f32x4 __attribute__((ext_vector_type(4)));
typedef float f32x16 __attribute__((ext_vector_type(16)));
typedef __bf16 bf16x8 __attribute__((ext_vector_type(8)));
typedef u32 u32x4 __attribute__((ext_vector_type(4)));

__device__ __forceinline__ u16 f2bf(float f) {
  unsigned int x = __float_as_uint(f);
  x = (x + 0x7fffu + ((x >> 16) & 1u)) >> 16;  // RNE
  return (u16)x;
}

__device__ __forceinline__ f32x4 mfma16(bf16x8 a, bf16x8 b, f32x4 c) {
  return __builtin_amdgcn_mfma_f32_16x16x32_bf16(a, b, c, 0, 0, 0);
}
__device__ __forceinline__ f32x16 mfma32(bf16x8 a, bf16x8 b, f32x16 c) {
  return __builtin_amdgcn_mfma_f32_32x32x16_bf16(a, b, c, 0, 0, 0);
}
// packs (lo,hi) -> u32 of 2 bf16 (low=lo), RNE
__device__ __forceinline__ u32 cvtpk_bf16(float lo, float hi) {
  u32 r;
  asm("v_cvt_pk_bf16_f32 %0, %1, %2" : "=v"(r) : "v"(lo), "v"(hi));
  return r;
}
__device__ __forceinline__ void gload_lds16(const u16* g, u16* l) {
  __builtin_amdgcn_global_load_lds((const __attribute__((address_space(1))) void*)g,
                                   (__attribute__((address_space(3))) void*)l, 16, 0, 0);
}

// ---------------- f32 -> bf16 cast (vectorized) ----------------
__global__ __launch_bounds__(256) void cast_bf16_kernel(const float4* __restrict__ in,
                                                        ushort4* __restrict__ out, int n4) {
  int i = blockIdx.x * 256 + threadIdx.x;
  int stride = gridDim.x * 256;
  for (; i < n4; i += stride) {
    float4 v = in[i];
    ushort4 o;
    o.x = f2bf(v.x); o.y = f2bf(v.y); o.z = f2bf(v.z); o.w = f2bf(v.w);
    out[i] = o;
  }
}

// ---------------- W [K][N] f32 -> WT [N][K] bf16 ----------------
__global__ __launch_bounds__(256) void wtrans_kernel(const float* __restrict__ W,
                                                     u16* __restrict__ WT) {
  __shared__ float tile[32][33];
  int k0 = blockIdx.x * 32, n0 = blockIdx.y * 32;
  int t = threadIdx.x, c = t & 31, r0 = t >> 5;
#pragma unroll
  for (int i = 0; i < 4; ++i)
    tile[r0 + i * 8][c] = W[(size_t)(k0 + r0 + i * 8) * D_ + n0 + c];
  __syncthreads();
#pragma unroll
  for (int i = 0; i < 4; ++i)
    WT[(size_t)(n0 + r0 + i * 8) * D_ + k0 + c] = f2bf(tile[c][r0 + i * 8]);
}

// ---------------- Vp [M][D] bf16 -> Vt [64 bh][64 dk][2048 s] ----------------
__global__ __launch_bounds__(256) void vtrans_kernel(const u16* __restrict__ Vp,
                                                     u16* __restrict__ Vt) {
  __shared__ u16 tile[64][65];
  int bx = blockIdx.x;  // 64 bh * 32 s-tiles
  int bh = bx >> 5;
  int s0 = (bx & 31) * 64;
  int b = bh >> 4, h = bh & 15;
  int t = threadIdx.x, c = t & 63, r0 = t >> 6;
#pragma unroll
  for (int i = 0; i < 16; ++i) {
    int s = r0 + i * 4;
    tile[s][c] = Vp[(size_t)(b * S_ + s0 + s) * D_ + h * 64 + c];
  }
  __syncthreads();
#pragma unroll
  for (int i = 0; i < 16; ++i) {
    int dk = r0 + i * 4;
    Vt[((size_t)bh * 64 + dk) * S_ + s0 + c] = tile[c][dk];
  }
}

// ---------------- GEMM: C[M][1024] = A @ WT^T + bias (m97 structure) ----------------
// 128x128 tile, BK=64, 4 waves (2x2), 4x4 16x16 frags; global_load_lds w=16,
// linear LDS [row][64] both sides.
template <bool OUT_F32>
__global__ __launch_bounds__(256) void gemm_kernel(const u16* __restrict__ A,
                                                   const u16* __restrict__ BT,
                                                   const float* __restrict__ bias,
                                                   void* __restrict__ out) {
  __shared__ __align__(16) u16 ldsA[128 * 64];
  __shared__ __align__(16) u16 ldsB[128 * 64];
  int bx = blockIdx.x;                  // 512 = 64 Mtiles * 8 Ntiles
  int swz = (bx & 7) * 64 + (bx >> 3);  // bijective XCD swizzle (512%8==0)
  int bm = swz >> 3, bn = swz & 7;
  int t = threadIdx.x, w = t >> 6, lane = t & 63;
  int wm = w >> 1, wn = w & 1;
  int l15 = lane & 15, hi = lane >> 4;

  f32x4 acc[4][4];
#pragma unroll
  for (int m = 0; m < 4; ++m)
#pragma unroll
    for (int n = 0; n < 4; ++n) acc[m][n] = (f32x4){0.f, 0.f, 0.f, 0.f};

  // staging: wave w owns rows [w*32, w*32+32); lane = (row&7)*8 + chunk -> linear LDS
  int srow = w * 32 + (lane >> 3);
  int schunk = lane & 7;
  const u16* Ag = A + (size_t)(bm * 128 + srow) * D_ + schunk * 8;
  const u16* Bg = BT + (size_t)(bn * 128 + srow) * D_ + schunk * 8;
  u16* lA = ldsA + w * 32 * 64;  // wave-uniform LDS base
  u16* lB = ldsB + w * 32 * 64;

  for (int kk = 0; kk < D_; kk += 64) {
    __syncthreads();
#pragma unroll
    for (int i = 0; i < 4; ++i) {
      gload_lds16(Ag + kk + i * 8 * D_, lA + i * 8 * 64);
      gload_lds16(Bg + kk + i * 8 * D_, lB + i * 8 * 64);
    }
    __syncthreads();  // compiler drains vmcnt before barrier -> LDS ready
#pragma unroll
    for (int ks = 0; ks < 2; ++ks) {
      bf16x8 af[4], bfr[4];
#pragma unroll
      for (int m = 0; m < 4; ++m)
        af[m] = *(const bf16x8*)(ldsA + (wm * 64 + m * 16 + l15) * 64 + (ks * 4 + hi) * 8);
#pragma unroll
      for (int n = 0; n < 4; ++n)
        bfr[n] = *(const bf16x8*)(ldsB + (wn * 64 + n * 16 + l15) * 64 + (ks * 4 + hi) * 8);
#pragma unroll
      for (int m = 0; m < 4; ++m)
#pragma unroll
        for (int n = 0; n < 4; ++n)
          acc[m][n] = mfma16(af[m], bfr[n], acc[m][n]);
    }
  }

#pragma unroll
  for (int m = 0; m < 4; ++m)
#pragma unroll
    for (int n = 0; n < 4; ++n) {
      int row = bm * 128 + wm * 64 + m * 16 + hi * 4;
      int col = bn * 128 + wn * 64 + n * 16 + l15;
      float bv = bias[col];
#pragma unroll
      for (int r = 0; r < 4; ++r) {
        float v = acc[m][n][r] + bv;
        if (OUT_F32)
          ((float*)out)[(size_t)(row + r) * D_ + col] = v;
        else
          ((u16*)out)[(size_t)(row + r) * D_ + col] = f2bf(v);
      }
    }
}

// ---------------- Flash attention, 8 waves x 32 q-rows, 32x32 MFMA ----------------
// Swapped QK^T: P = mfma(A=K, B=Q) -> C[key(reg)][q=lane&31]; lane-pair (l,l+32)
// holds the full 128-key P row of q=l&31 in regs. Softmax state (m,l) is per
// lane-q; O's 16 C-regs are 16 DIFFERENT q rows, so the rescale alpha is
// shfl-redistributed per row (gated: only when some lane's tile-max > running
// max — otherwise alpha==1 exactly). Repack P via v_cvt_pk_bf16_f32 + 2 shfl.
__global__ __launch_bounds__(512) void attn_kernel(const u16* __restrict__ Qp,
                                                   const u16* __restrict__ Kp,
                                                   const u16* __restrict__ Vt,
                                                   u16* __restrict__ ctx) {
  __shared__ __align__(16) u16 Kl[128 * 64];
  __shared__ __align__(16) u16 Vl[64 * 128];

  int bx = blockIdx.x;                 // 512 = 64 bh * 8 qtiles
  int bh = (bx & 7) * 8 + (bx >> 6);   // 8 blocks of same bh per XCD
  int qt = (bx >> 3) & 7;
  int b = bh >> 4, h = bh & 15;

  int t = threadIdx.x, w = t >> 6, lane = t & 63;
  int l31 = lane & 31, hh = lane >> 5;
  int qglob = qt * 256 + w * 32;       // wave's 32 q rows

  // Q B-frags (pre-scaled by 1/sqrt(DK)=0.125, exact in bf16)
  bf16x8 qf[4];
  {
    const u16* qptr = Qp + (size_t)(b * S_ + qglob + l31) * D_ + h * 64;
#pragma unroll
    for (int ks = 0; ks < 4; ++ks) {
      bf16x8 v = *(const bf16x8*)(qptr + ks * 16 + hh * 8);
#pragma unroll
      for (int j = 0; j < 8; ++j) v[j] = (__bf16)((float)v[j] * 0.125f);
      qf[ks] = v;
    }
  }

  float m = -1e30f, l = 0.f;
  f32x16 O0, O1;
#pragma unroll
  for (int i = 0; i < 16; ++i) { O0[i] = 0.f; O1[i] = 0.f; }

  // staging (global->reg->LDS): K 128x8 chunk-slots, V 64x16; 512 threads, 2 each
  const u16* Kbase = Kp + (size_t)(b * S_) * D_ + h * 64;
  const u16* Vbase = Vt + (size_t)bh * 64 * S_;
  int krow = t >> 3, kc = t & 7;   // K rows krow, krow+64
  int vrow = t >> 4, vc = t & 15;  // V rows vrow, vrow+32
  u32x4 kreg0, kreg1, vreg0, vreg1;
  kreg0 = *(const u32x4*)(Kbase + (size_t)(krow)*D_ + kc * 8);
  kreg1 = *(const u32x4*)(Kbase + (size_t)(krow + 64) * D_ + kc * 8);
  vreg0 = *(const u32x4*)(Vbase + (size_t)(vrow)*S_ + vc * 8);
  vreg1 = *(const u32x4*)(Vbase + (size_t)(vrow + 32) * S_ + vc * 8);

  for (int kt = 0; kt < 16; ++kt) {
    __syncthreads();  // previous tile fully consumed
    // swizzled ds_writes: K chunk pi = c ^ (key&7); V pi = (c&8)|((c^dk)&7)
    *(u32x4*)(Kl + krow * 64 + ((kc ^ (krow & 7)) << 3)) = kreg0;
    *(u32x4*)(Kl + (krow + 64) * 64 + ((kc ^ (krow & 7)) << 3)) = kreg1;
    *(u32x4*)(Vl + vrow * 128 + (((vc & 8) | ((vc ^ vrow) & 7)) << 3)) = vreg0;
    *(u32x4*)(Vl + (vrow + 32) * 128 + (((vc & 8) | ((vc ^ vrow) & 7)) << 3)) = vreg1;
    if (kt < 15) {  // T14: issue next-tile loads; consumed after next barrier
      kreg0 = *(const u32x4*)(Kbase + (size_t)(kt * 128 + 128 + krow) * D_ + kc * 8);
      kreg1 = *(const u32x4*)(Kbase + (size_t)(kt * 128 + 192 + krow) * D_ + kc * 8);
      vreg0 = *(const u32x4*)(Vbase + (size_t)(vrow)*S_ + kt * 128 + 128 + vc * 8);
      vreg1 = *(const u32x4*)(Vbase + (size_t)(vrow + 32) * S_ + kt * 128 + 128 + vc * 8);
    }
    __syncthreads();  // ds_writes visible

    // ---- QK^T: 4 C-tiles of 32 keys ----
    f32x16 pct[4];
#pragma unroll
    for (int ct = 0; ct < 4; ++ct) {
      f32x16 p;
#pragma unroll
      for (int i = 0; i < 16; ++i) p[i] = 0.f;
#pragma unroll
      for (int ks = 0; ks < 4; ++ks) {
        int key = ct * 32 + l31;
        int cl = 2 * ks + hh;  // logical 16B chunk in K row
        bf16x8 kf = *(const bf16x8*)(Kl + key * 64 + ((cl ^ (key & 7)) << 3));
        p = mfma32(kf, qf[ks], p);
      }
      pct[ct] = p;
    }

    // ---- online softmax (per q = l31; lane-pair shares via shfl_xor 32) ----
    float pm = pct[0][0];
#pragma unroll
    for (int ct = 0; ct < 4; ++ct)
#pragma unroll
      for (int i = 0; i < 16; ++i) pm = fmaxf(pm, pct[ct][i]);
    pm = fmaxf(pm, __shfl_xor(pm, 32, 64));

    if (!__all(pm <= m)) {  // rescale only when some row's max grew (else alpha==1)
      float mn = fmaxf(m, pm);
      float alpha = __expf(m - mn);
      m = mn;
      l *= alpha;
#pragma unroll
      for (int i = 0; i < 16; ++i) {  // O rows are q=(i&3)+8*(i>>2)+4*hh, NOT lane-q
        float a = __shfl(alpha, (i & 3) + 8 * (i >> 2) + 4 * hh, 64);
        O0[i] *= a;
        O1[i] *= a;
      }
    }

    float ls = 0.f;
#pragma unroll
    for (int ct = 0; ct < 4; ++ct)
#pragma unroll
      for (int i = 0; i < 16; ++i) {
        float e = __expf(pct[ct][i] - m);
        pct[ct][i] = e;
        ls += e;
      }
    l += ls + __shfl_xor(ls, 32, 64);

    // ---- repack P (T12) + PV ----
#pragma unroll
    for (int ct = 0; ct < 4; ++ct) {
#pragma unroll
      for (int ks2 = 0; ks2 < 2; ++ks2) {
        u32 A0 = cvtpk_bf16(pct[ct][8 * ks2 + 0], pct[ct][8 * ks2 + 1]);
        u32 A1 = cvtpk_bf16(pct[ct][8 * ks2 + 2], pct[ct][8 * ks2 + 3]);
        u32 B0 = cvtpk_bf16(pct[ct][8 * ks2 + 4], pct[ct][8 * ks2 + 5]);
        u32 B1 = cvtpk_bf16(pct[ct][8 * ks2 + 6], pct[ct][8 * ks2 + 7]);
        u32 s0 = __shfl_xor((int)(hh ? A0 : B0), 32, 64);
        u32 s1 = __shfl_xor((int)(hh ? A1 : B1), 32, 64);
        u32x4 fw;
        fw[0] = hh ? s0 : A0;
        fw[1] = hh ? s1 : A1;
        fw[2] = hh ? B0 : s0;
        fw[3] = hh ? B1 : s1;
        bf16x8 pf = __builtin_bit_cast(bf16x8, fw);
        int cl = ct * 4 + 2 * ks2 + hh;  // logical chunk in V row (key/8)
#pragma unroll
        for (int dkh = 0; dkh < 2; ++dkh) {
          int dk = l31 + dkh * 32;
          bf16x8 vf = *(const bf16x8*)(Vl + dk * 128 + (((cl & 8) | ((cl ^ dk) & 7)) << 3));
          if (dkh == 0) O0 = mfma32(pf, vf, O0);
          else          O1 = mfma32(pf, vf, O1);
        }
      }
    }
  }

  // ---- epilogue: normalize rows; O C-layout row q = (r&3)+8*(r>>2)+4*hh ----
#pragma unroll
  for (int r = 0; r < 16; ++r) {
    int ql = (r & 3) + 8 * (r >> 2) + 4 * hh;
    float lr = __shfl(l, ql, 64);  // l lives at lane q (both halves identical)
    float inv = 1.0f / lr;
    u16* cp = ctx + (size_t)(b * S_ + qglob + ql) * D_ + h * 64;
    cp[l31] = f2bf(O0[r] * inv);
    cp[l31 + 32] = f2bf(O1[r] * inv);
  }
}

extern "C" void kernel_launch(void* const* d_in, const int* in_sizes, int n_in,
                              void* d_out, int out_size, void* d_ws, size_t ws_size,
                              hipStream_t stream) {
  const float* query = (const float*)d_in[0];
  const float* key   = (const float*)d_in[1];
  const float* value = (const float*)d_in[2];
  const float* Wq = (const float*)d_in[3];
  const float* bq = (const float*)d_in[4];
  const float* Wk = (const float*)d_in[5];
  const float* bk = (const float*)d_in[6];
  const float* Wv = (const float*)d_in[7];
  const float* bv = (const float*)d_in[8];
  const float* Wo = (const float*)d_in[9];
  const float* bo = (const float*)d_in[10];

  char* ws = (char*)d_ws;
  const size_t WT_BYTES  = (size_t)D_ * D_ * 2;
  const size_t MAT_BYTES = (size_t)M_ * D_ * 2;
  u16* WTq = (u16*)(ws);
  u16* WTk = (u16*)(ws + WT_BYTES);
  u16* WTv = (u16*)(ws + 2 * WT_BYTES);
  u16* WTo = (u16*)(ws + 3 * WT_BYTES);
  u16* Xb  = (u16*)(ws + 4 * WT_BYTES);
  u16* Qp  = (u16*)(ws + 4 * WT_BYTES + MAT_BYTES);
  u16* Kp  = (u16*)(ws + 4 * WT_BYTES + 2 * MAT_BYTES);
  u16* Vp  = (u16*)(ws + 4 * WT_BYTES + 3 * MAT_BYTES);
  u16* Vt  = Xb;   // input-cast buffer free after its projection
  u16* ctx = Vp;   // Vp free after vtrans

  dim3 blk(256);
  dim3 wgrid(32, 32);
  wtrans_kernel<<<wgrid, blk, 0, stream>>>(Wq, WTq);
  wtrans_kernel<<<wgrid, blk, 0, stream>>>(Wk, WTk);
  wtrans_kernel<<<wgrid, blk, 0, stream>>>(Wv, WTv);
  wtrans_kernel<<<wgrid, blk, 0, stream>>>(Wo, WTo);

  const int n4 = M_ * D_ / 4;
  cast_bf16_kernel<<<2048, blk, 0, stream>>>((const float4*)query, (ushort4*)Xb, n4);
  gemm_kernel<false><<<512, blk, 0, stream>>>(Xb, WTq, bq, Qp);
  cast_bf16_kernel<<<2048, blk, 0, stream>>>((const float4*)key, (ushort4*)Xb, n4);
  gemm_kernel<false><<<512, blk, 0, stream>>>(Xb, WTk, bk, Kp);
  cast_bf16_kernel<<<2048, blk, 0, stream>>>((const float4*)value, (ushort4*)Xb, n4);
  gemm_kernel<false><<<512, blk, 0, stream>>>(Xb, WTv, bv, Vp);
  vtrans_kernel<<<2048, blk, 0, stream>>>(Vp, Vt);
  attn_kernel<<<512, dim3(512), 0, stream>>>(Qp, Kp, Vt, ctx);
  gemm_kernel<true><<<512, blk, 0, stream>>>(ctx, WTo, bo, d_out);
}